// Round 16
// baseline (2307.910 us; speedup 1.0000x reference)
//
#include <hip/hip_runtime.h>
#include <cstdint>
#include <cstddef>

#define T_STEPS 1024
#define NB 64
#define DIN 256
#define DH 256
#define DW 512            // DIN + DH (row width of each W)
#define G4 1024           // 4*DH gate rows

typedef _Float16 h2 __attribute__((ext_vector_type(2)));
typedef _Float16 h4 __attribute__((ext_vector_type(4)));
typedef _Float16 h8 __attribute__((ext_vector_type(8)));
typedef float f4 __attribute__((ext_vector_type(4)));
typedef float f32x4 __attribute__((ext_vector_type(4)));
typedef int i4v __attribute__((ext_vector_type(4)));

static __device__ __forceinline__ h2 sl2(h8 v, int m) {
  h2 r; r[0] = v[2 * m]; r[1] = v[2 * m + 1]; return r;
}

static __device__ __forceinline__ float fdot2(h2 a, h2 b, float c) {
#if __has_builtin(__builtin_amdgcn_fdot2)
  return __builtin_amdgcn_fdot2(a, b, c, false);
#else
  return c + (float)a[0]*(float)b[0] + (float)a[1]*(float)b[1];
#endif
}

static __device__ __forceinline__ float rcp_(float x) {
#if __has_builtin(__builtin_amdgcn_rcpf)
  return __builtin_amdgcn_rcpf(x);
#else
  return 1.0f / x;
#endif
}

static __device__ __forceinline__ float sigmoid_(float x) {
  return rcp_(1.f + __expf(-x));
}
static __device__ __forceinline__ float tanh_(float x) {
  float e = __expf(2.f * x);
  return 1.f - 2.f * rcp_(e + 1.f);
}

// Pairwise lane swap (0<->1, ...) via DPP quad_perm [1,0,3,2] — pure VALU.
static __device__ __forceinline__ float dpp_swap1(float x) {
  int r = __builtin_amdgcn_update_dpp(0, __builtin_bit_cast(int, x),
                                      0xB1, 0xF, 0xF, true);
  return __builtin_bit_cast(float, r);
}

// ---------------------------------------------------------------------------
// Weight pre-conversion:
//  wxfs: x-part f16, MFMA-staging order (r15, verified)
//  wrowh[gr][kp]: h-part f16 row-major (klstm)
// ---------------------------------------------------------------------------
__global__ void kconv_w(const float* __restrict__ Wf, const float* __restrict__ Wi,
                        const float* __restrict__ Wg, const float* __restrict__ Wo,
                        h2* __restrict__ wxfs, h2* __restrict__ wrowh) {
  int kp = blockIdx.x >> 2;
  int gate = blockIdx.x & 3;
  int j = threadIdx.x;
  const float* W = gate == 0 ? Wf : gate == 1 ? Wi : gate == 2 ? Wg : Wo;
  const float* row = W + (size_t)j * DW;
  h2 v; v[0] = (_Float16)row[2*kp]; v[1] = (_Float16)row[2*kp + 1];
  {
    int ks = kp >> 4, lg = (kp >> 2) & 3, slot = kp & 3;
    int nt = j >> 4, li = j & 15;
    size_t h8idx = (((size_t)gate * 8 + ks) * 16 + nt) * 64 + lg * 16 + li;
    wxfs[h8idx * 4 + slot] = v;
  }
  h2 u; u[0] = (_Float16)row[DIN + 2*kp]; u[1] = (_Float16)row[DIN + 2*kp + 1];
  wrowh[((size_t)gate * DH + j) * 128 + kp] = u;
}

// ---------------------------------------------------------------------------
// Phase 1 (MFMA v3, r15-exact — 62us measured): Xg = x.Wx^T + bias.
// ---------------------------------------------------------------------------
__launch_bounds__(256, 2)
__global__ void kxgemm(const float* __restrict__ x,
                       const h8* __restrict__ wxfs,
                       const float* __restrict__ bf, const float* __restrict__ bi,
                       const float* __restrict__ bg, const float* __restrict__ bo,
                       _Float16* __restrict__ Xg,
                       int t0) {
  __shared__ char pool[65536];
  h8 (*xsf)[8][64] = (h8(*)[8][64])pool;               // 32KB A-frags
  h8 (*bs)[1024] = (h8(*)[1024])(pool + 32768);        // 2x16KB B slabs

  int tid = threadIdx.x;
  int l = tid & 63;
  int w = tid >> 6;
  int li = l & 15, lg = l >> 4;
  int tl = blockIdx.x >> 2;
  int nb = blockIdx.x & 3;
  int m0 = w * 16;

#pragma unroll
  for (int i = 0; i < 8; ++i) {
    int hi = tid + 256 * i;
    int sw  = hi >> 9;
    int sks = (hi >> 6) & 7;
    int sl  = hi & 63;
    int sli = sl & 15, slg = sl >> 4;
    const float* src = x + ((size_t)(t0 + tl) * NB + sw * 16 + sli) * DIN
                     + sks * 32 + slg * 8;
    f4 a0 = *(const f4*)src;
    f4 a1 = *(const f4*)(src + 4);
    h8 a;
    a[0] = (_Float16)a0[0]; a[1] = (_Float16)a0[1];
    a[2] = (_Float16)a0[2]; a[3] = (_Float16)a0[3];
    a[4] = (_Float16)a1[0]; a[5] = (_Float16)a1[1];
    a[6] = (_Float16)a1[2]; a[7] = (_Float16)a1[3];
    xsf[sw][sks][sl] = a;
  }
  {
    const h8* wsrc = wxfs + (size_t)(nb * 8 + 0) * 1024;
#pragma unroll
    for (int i = 0; i < 4; ++i) bs[0][tid + 256 * i] = wsrc[tid + 256 * i];
  }
  __syncthreads();

  f32x4 acc[16];
#pragma unroll
  for (int nt = 0; nt < 16; ++nt) {
    acc[nt][0] = 0.f; acc[nt][1] = 0.f; acc[nt][2] = 0.f; acc[nt][3] = 0.f;
  }

  for (int ks = 0; ks < 8; ++ks) {
    int buf = ks & 1;
    h8 ld0, ld1, ld2, ld3;
    if (ks < 7) {
      const h8* wn = wxfs + (size_t)(nb * 8 + ks + 1) * 1024;
      ld0 = wn[tid]; ld1 = wn[tid + 256]; ld2 = wn[tid + 512]; ld3 = wn[tid + 768];
    }
    h8 a = xsf[w][ks][l];
#pragma unroll
    for (int nt = 0; nt < 16; ++nt) {
      h8 bb = bs[buf][nt * 64 + l];
      acc[nt] = __builtin_amdgcn_mfma_f32_16x16x32_f16(a, bb, acc[nt], 0, 0, 0);
    }
    if (ks < 7) {
      h8* bt = bs[buf ^ 1];
      bt[tid] = ld0; bt[tid + 256] = ld1; bt[tid + 512] = ld2; bt[tid + 768] = ld3;
    }
    __syncthreads();
  }

  _Float16* osw = (_Float16*)(pool + (size_t)w * 8448);   // [16][264]
  const float* biasp = nb == 0 ? bf : nb == 1 ? bi : nb == 2 ? bg : bo;
#pragma unroll
  for (int nt = 0; nt < 16; ++nt) {
    float bv = biasp[nt * 16 + li];
#pragma unroll
    for (int r = 0; r < 4; ++r)
      osw[(lg * 4 + r) * 264 + nt * 16 + li] = (_Float16)(acc[nt][r] + bv);
  }
  _Float16* og = Xg + (size_t)tl * 65536 + (size_t)m0 * 1024 + nb * 256;
#pragma unroll
  for (int it = 0; it < 8; ++it) {
    int i = l + 64 * it;
    int row = i >> 5, c8 = i & 31;
    h8 v = *(const h8*)(const void*)&osw[row * 264 + c8 * 8];
    *(h8*)(void*)(og + (size_t)row * 1024 + c8 * 8) = v;
  }
}

// ---------------------------------------------------------------------------
// Phase 2: sequential LSTM, r7 skeleton with EXPLICIT 3-TIER weights sized to
// the HW budget (2 waves/SIMD x 256 regs = 128 arch + 128 acc per wave):
//  chunks 0..5  (24 h8 =  96 regs) arch VGPRs, demand ~126 <= 128 grant
//  chunks 6..13 (32 h8 = 128 AGPRs) explicit v_accvgpr_write once +
//               v_accvgpr_read per use (1 full-rate VALU op each, replacing
//               the compiler's ~350 junk copies for its implicit overflow)
//  chunks 14..15 (8 h8) in LDS + 16 h-broadcasts = 24 LDS reads/step (was 32)
// ---------------------------------------------------------------------------
#define CHV(M) M(0) M(1) M(2) M(3) M(4) M(5)
#define CHA(M) M(6) M(7) M(8) M(9) M(10) M(11) M(12) M(13)
#define HPAD 68   // h2 stride of one K-half in hbuf (64 + 4 skew)

__global__ __launch_bounds__(512, 1)
void klstm(const h2* __restrict__ wrowh,
           const _Float16* __restrict__ Xg,
           const float* __restrict__ hsrc, const float* __restrict__ csrc,
           float* __restrict__ out,
           float* __restrict__ hN, float* __restrict__ cN,
           int t0, int Tc) {
  __shared__ h8 wtail[8][512];         // 64KB: [gate*2 + (chunk-14)][tid]
  __shared__ h2 hbuf[2][2 * HPAD];     // double-buffered h, halves skewed

  int tid = threadIdx.x;
  int b = blockIdx.x;
  int p = tid & 1;
  int j = tid >> 1;
  int hoff = p * HPAD;

  const h2* rowF = wrowh + ((size_t)0 * DH + j) * 128 + p * 64;
  const h2* rowI = wrowh + ((size_t)1 * DH + j) * 128 + p * 64;
  const h2* rowG = wrowh + ((size_t)2 * DH + j) * 128 + p * 64;
  const h2* rowO = wrowh + ((size_t)3 * DH + j) * 128 + p * 64;

  // --- arch tier: chunks 0..5, named + pinned ---
#define DECLW(i) h8 WF_##i, WI_##i, WG_##i, WO_##i;
  CHV(DECLW)
#undef DECLW
#define LOADW(i) \
  WF_##i = *(const h8*)(const void*)(rowF + 4 * (i)); \
  WI_##i = *(const h8*)(const void*)(rowI + 4 * (i)); \
  WG_##i = *(const h8*)(const void*)(rowG + 4 * (i)); \
  WO_##i = *(const h8*)(const void*)(rowO + 4 * (i));
  CHV(LOADW)
#undef LOADW
#define PINW(i) \
  asm volatile("" : "+v"(WF_##i)); asm volatile("" : "+v"(WI_##i)); \
  asm volatile("" : "+v"(WG_##i)); asm volatile("" : "+v"(WO_##i));
  CHV(PINW)
#undef PINW

  // --- acc tier: chunks 6..13 into AGPRs via explicit writes ---
#define DECLA1(Gt, c) int A##Gt##_##c##_0, A##Gt##_##c##_1, A##Gt##_##c##_2, A##Gt##_##c##_3;
#define DECLA(c) DECLA1(F, c) DECLA1(I, c) DECLA1(G, c) DECLA1(O, c)
  CHA(DECLA)
#undef DECLA
#define WRA1(Gt, c, rowp) { \
    i4v iv = __builtin_bit_cast(i4v, *(const h8*)(const void*)((rowp) + 4 * (c))); \
    asm volatile("v_accvgpr_write_b32 %0, %1" : "=a"(A##Gt##_##c##_0) : "v"(iv[0])); \
    asm volatile("v_accvgpr_write_b32 %0, %1" : "=a"(A##Gt##_##c##_1) : "v"(iv[1])); \
    asm volatile("v_accvgpr_write_b32 %0, %1" : "=a"(A##Gt##_##c##_2) : "v"(iv[2])); \
    asm volatile("v_accvgpr_write_b32 %0, %1" : "=a"(A##Gt##_##c##_3) : "v"(iv[3])); }
#define WRA(c) WRA1(F, c, rowF) WRA1(I, c, rowI) WRA1(G, c, rowG) WRA1(O, c, rowO)
  CHA(WRA)
#undef WRA

  // --- LDS tier: chunks 14..15 ---
#pragma unroll
  for (int tt = 0; tt < 2; ++tt) {
    wtail[0 + tt][tid] = *(const h8*)(const void*)(rowF + 4 * (14 + tt));
    wtail[2 + tt][tid] = *(const h8*)(const void*)(rowI + 4 * (14 + tt));
    wtail[4 + tt][tid] = *(const h8*)(const void*)(rowG + 4 * (14 + tt));
    wtail[6 + tt][tid] = *(const h8*)(const void*)(rowO + 4 * (14 + tt));
  }

  float creg = csrc[(size_t)b * DH + j];
  if (tid < 128) {
    int pos = (tid < 64) ? tid : (HPAD + tid - 64);
    h2 hv;
    hv[0] = (_Float16)hsrc[(size_t)b * DH + 2 * tid];
    hv[1] = (_Float16)hsrc[(size_t)b * DH + 2 * tid + 1];
    hbuf[0][pos] = hv;
  }
  __syncthreads();

  const size_t xstep = (size_t)NB * G4;
  const _Float16* xpA = Xg + (size_t)b * G4 + p * 512 + j;        // f or g
  const _Float16* xpB = xpA + 256;                                // i or o
  float xA = (float)xpA[0], xB = (float)xpB[0];
  float hlast = 0.f;

  for (int t = 0; t < Tc; ++t) {
    float xAn = 0.f, xBn = 0.f;
    if (t + 1 < Tc) {
      xAn = (float)xpA[(size_t)(t + 1) * xstep];
      xBn = (float)xpB[(size_t)(t + 1) * xstep];
    }
    const h2* hb = hbuf[t & 1] + hoff;

    float accF = p ? 0.f : xA;
    float accI = p ? 0.f : xB;
    float accG = p ? xA : 0.f;
    float accO = p ? xB : 0.f;

    // arch-tier chunks
#define DOTCH(i) { \
    h8 hv = *(const h8*)(const void*)(hb + 4 * (i)); \
    accF = fdot2(sl2(WF_##i,0), sl2(hv,0), accF); \
    accF = fdot2(sl2(WF_##i,1), sl2(hv,1), accF); \
    accF = fdot2(sl2(WF_##i,2), sl2(hv,2), accF); \
    accF = fdot2(sl2(WF_##i,3), sl2(hv,3), accF); \
    accI = fdot2(sl2(WI_##i,0), sl2(hv,0), accI); \
    accI = fdot2(sl2(WI_##i,1), sl2(hv,1), accI); \
    accI = fdot2(sl2(WI_##i,2), sl2(hv,2), accI); \
    accI = fdot2(sl2(WI_##i,3), sl2(hv,3), accI); \
    accG = fdot2(sl2(WG_##i,0), sl2(hv,0), accG); \
    accG = fdot2(sl2(WG_##i,1), sl2(hv,1), accG); \
    accG = fdot2(sl2(WG_##i,2), sl2(hv,2), accG); \
    accG = fdot2(sl2(WG_##i,3), sl2(hv,3), accG); \
    accO = fdot2(sl2(WO_##i,0), sl2(hv,0), accO); \
    accO = fdot2(sl2(WO_##i,1), sl2(hv,1), accO); \
    accO = fdot2(sl2(WO_##i,2), sl2(hv,2), accO); \
    accO = fdot2(sl2(WO_##i,3), sl2(hv,3), accO); }
    CHV(DOTCH)
#undef DOTCH

    // acc-tier chunks: read AGPR -> fdot2
#define RD1(Gt, c, k, dst) \
    asm volatile("v_accvgpr_read_b32 %0, %1" : "=v"(dst) : "a"(A##Gt##_##c##_##k));
#define DOTA(c) { \
    h8 hv = *(const h8*)(const void*)(hb + 4 * (c)); \
    h2 hv0 = sl2(hv,0), hv1 = sl2(hv,1), hv2x = sl2(hv,2), hv3 = sl2(hv,3); \
    int r0, r1, r2, r3; \
    RD1(F, c, 0, r0) RD1(F, c, 1, r1) RD1(F, c, 2, r2) RD1(F, c, 3, r3) \
    accF = fdot2(__builtin_bit_cast(h2, r0), hv0, accF); \
    accF = fdot2(__builtin_bit_cast(h2, r1), hv1, accF); \
    accF = fdot2(__builtin_bit_cast(h2, r2), hv2x, accF); \
    accF = fdot2(__builtin_bit_cast(h2, r3), hv3, accF); \
    RD1(I, c, 0, r0) RD1(I, c, 1, r1) RD1(I, c, 2, r2) RD1(I, c, 3, r3) \
    accI = fdot2(__builtin_bit_cast(h2, r0), hv0, accI); \
    accI = fdot2(__builtin_bit_cast(h2, r1), hv1, accI); \
    accI = fdot2(__builtin_bit_cast(h2, r2), hv2x, accI); \
    accI = fdot2(__builtin_bit_cast(h2, r3), hv3, accI); \
    RD1(G, c, 0, r0) RD1(G, c, 1, r1) RD1(G, c, 2, r2) RD1(G, c, 3, r3) \
    accG = fdot2(__builtin_bit_cast(h2, r0), hv0, accG); \
    accG = fdot2(__builtin_bit_cast(h2, r1), hv1, accG); \
    accG = fdot2(__builtin_bit_cast(h2, r2), hv2x, accG); \
    accG = fdot2(__builtin_bit_cast(h2, r3), hv3, accG); \
    RD1(O, c, 0, r0) RD1(O, c, 1, r1) RD1(O, c, 2, r2) RD1(O, c, 3, r3) \
    accO = fdot2(__builtin_bit_cast(h2, r0), hv0, accO); \
    accO = fdot2(__builtin_bit_cast(h2, r1), hv1, accO); \
    accO = fdot2(__builtin_bit_cast(h2, r2), hv2x, accO); \
    accO = fdot2(__builtin_bit_cast(h2, r3), hv3, accO); }
    CHA(DOTA)
#undef DOTA
#undef RD1

    // LDS-tier chunks 14..15
#pragma unroll
    for (int tt = 0; tt < 2; ++tt) {
      h8 hv = *(const h8*)(const void*)(hb + 4 * (14 + tt));
      h8 wf = wtail[0 + tt][tid];
      h8 wi = wtail[2 + tt][tid];
      h8 wg = wtail[4 + tt][tid];
      h8 wo = wtail[6 + tt][tid];
#pragma unroll
      for (int m = 0; m < 4; ++m) {
        accF = fdot2(sl2(wf, m), sl2(hv, m), accF);
        accI = fdot2(sl2(wi, m), sl2(hv, m), accI);
        accG = fdot2(sl2(wg, m), sl2(hv, m), accG);
        accO = fdot2(sl2(wo, m), sl2(hv, m), accO);
      }
    }

    accF += dpp_swap1(accF);
    accI += dpp_swap1(accI);
    accG += dpp_swap1(accG);
    accO += dpp_swap1(accO);

    float f_ = sigmoid_(accF);
    float i_ = sigmoid_(accI);
    float g_ = tanh_(accG);
    float o_ = sigmoid_(accO);

    creg = f_ * creg + i_ * g_;
    float hn = o_ * tanh_(creg);
    hlast = hn;
    if (p == 0) {
      out[((size_t)(t0 + t) * NB + b) * DH + j] = hn;
    } else {
      int pos = (j < 128) ? j : (2 * HPAD + (j - 128));
      ((_Float16*)hbuf[(t + 1) & 1])[pos] = (_Float16)hn;
    }
    __syncthreads();
    xA = xAn; xB = xBn;
  }

  if (p == 0) {
    hN[(size_t)b * DH + j] = hlast;
    cN[(size_t)b * DH + j] = creg;
  }
}

// ---------------------------------------------------------------------------
extern "C" void kernel_launch(void* const* d_in, const int* in_sizes, int n_in,
                              void* d_out, int out_size, void* d_ws, size_t ws_size,
                              hipStream_t stream) {
  if (n_in < 11) return;
  const float* x  = (const float*)d_in[0];
  const float* h0 = (const float*)d_in[1];
  const float* c0 = (const float*)d_in[2];
  const float* Wf = (const float*)d_in[3];
  const float* bf = (const float*)d_in[4];
  const float* Wi = (const float*)d_in[5];
  const float* bi = (const float*)d_in[6];
  const float* Wg = (const float*)d_in[7];
  const float* bg = (const float*)d_in[8];
  const float* Wo = (const float*)d_in[9];
  const float* bo = (const float*)d_in[10];

  float* out = (float*)d_out;
  float* hN = out + (size_t)T_STEPS * NB * DH;
  float* cN = hN + (size_t)NB * DH;

  // ws layout: [Xg ring: Tc*128KB][wxfs 512KB][wrowh 512KB]
  const size_t wxfBytes  = (size_t)G4 * 128 * sizeof(h2);   // 512KB
  const size_t wrowBytes = (size_t)G4 * 128 * sizeof(h2);   // 512KB
  const size_t fixedBytes = wxfBytes + wrowBytes;
  size_t avail = (ws_size > fixedBytes + 512) ? ws_size - fixedBytes - 512 : 0;
  const size_t perT = (size_t)NB * G4 * 2;  // 128KB per time step
  int Tc = (int)(avail / perT);
  if (Tc > T_STEPS) Tc = T_STEPS;
  if (Tc < 1) Tc = 1;

  _Float16* Xg = (_Float16*)d_ws;
  size_t xgBytes = ((size_t)Tc * perT + 255) / 256 * 256;
  h2* wxfs  = (h2*)((char*)d_ws + xgBytes);
  h2* wrowh = (h2*)((char*)d_ws + xgBytes + wxfBytes);

  kconv_w<<<dim3(512), dim3(256), 0, stream>>>(Wf, Wi, Wg, Wo, wxfs, wrowh);

  for (int t0 = 0; t0 < T_STEPS; t0 += Tc) {
    int tc = (T_STEPS - t0 < Tc) ? (T_STEPS - t0) : Tc;
    kxgemm<<<dim3(tc * 4), dim3(256), 0, stream>>>(x, (const h8*)wxfs,
                                                   bf, bi, bg, bo, Xg, t0);
    const float* hs = (t0 == 0) ? h0 : hN;
    const float* cs = (t0 == 0) ? c0 : cN;
    klstm<<<dim3(NB), dim3(512), 0, stream>>>(wrowh, Xg, hs, cs,
                                              out, hN, cN, t0, tc);
  }
}

// Round 17
// 1243.722 us; speedup vs baseline: 1.8556x; 1.8556x over previous
//
#include <hip/hip_runtime.h>
#include <cstdint>
#include <cstddef>

#define T_STEPS 1024
#define NB 64
#define DIN 256
#define DH 256
#define DW 512            // DIN + DH (row width of each W)
#define G4 1024           // 4*DH gate rows

typedef _Float16 h2 __attribute__((ext_vector_type(2)));
typedef _Float16 h4 __attribute__((ext_vector_type(4)));
typedef _Float16 h8 __attribute__((ext_vector_type(8)));
typedef float f4 __attribute__((ext_vector_type(4)));
typedef float f32x4 __attribute__((ext_vector_type(4)));
typedef int i4v __attribute__((ext_vector_type(4)));

static __device__ __forceinline__ float rcp_(float x) {
#if __has_builtin(__builtin_amdgcn_rcpf)
  return __builtin_amdgcn_rcpf(x);
#else
  return 1.0f / x;
#endif
}

static __device__ __forceinline__ float sigmoid_(float x) {
  return rcp_(1.f + __expf(-x));
}
static __device__ __forceinline__ float tanh_(float x) {
  float e = __expf(2.f * x);
  return 1.f - 2.f * rcp_(e + 1.f);
}

static __device__ __forceinline__ int sdot4_(int a, int b, int c) {
#if __has_builtin(__builtin_amdgcn_sdot4)
  return __builtin_amdgcn_sdot4(a, b, c, false);
#else
  int r = c;
#pragma unroll
  for (int k = 0; k < 4; ++k)
    r += (int)(signed char)(a >> (8 * k)) * (int)(signed char)(b >> (8 * k));
  return r;
#endif
}

// Pairwise lane swap (0<->1, ...) via DPP quad_perm [1,0,3,2] — pure VALU.
static __device__ __forceinline__ float dpp_swap1(float x) {
  int r = __builtin_amdgcn_update_dpp(0, __builtin_bit_cast(int, x),
                                      0xB1, 0xF, 0xF, true);
  return __builtin_bit_cast(float, r);
}

// ---------------------------------------------------------------------------
// x-part staging conversion (r15-exact): wxfs MFMA-staging order.
// ---------------------------------------------------------------------------
__global__ void kconv_w(const float* __restrict__ Wf, const float* __restrict__ Wi,
                        const float* __restrict__ Wg, const float* __restrict__ Wo,
                        h2* __restrict__ wxfs) {
  int kp = blockIdx.x >> 2;
  int gate = blockIdx.x & 3;
  int j = threadIdx.x;
  const float* W = gate == 0 ? Wf : gate == 1 ? Wi : gate == 2 ? Wg : Wo;
  const float* row = W + (size_t)j * DW;
  h2 v; v[0] = (_Float16)row[2*kp]; v[1] = (_Float16)row[2*kp + 1];
  int ks = kp >> 4, lg = (kp >> 2) & 3, slot = kp & 3;
  int nt = j >> 4, li = j & 15;
  size_t h8idx = (((size_t)gate * 8 + ks) * 16 + nt) * 64 + lg * 16 + li;
  wxfs[h8idx * 4 + slot] = v;
}

// ---------------------------------------------------------------------------
// h-part int8 quantization: per-row scale s = amax/127; wq[gr][256] i8;
// cs[gr] = s/127 (combined scale: preact_h = cs * (int dot)).
// grid 4 blocks (gate), 256 threads (j = row within gate).
// ---------------------------------------------------------------------------
__global__ void kscale(const float* __restrict__ Wf, const float* __restrict__ Wi,
                       const float* __restrict__ Wg, const float* __restrict__ Wo,
                       signed char* __restrict__ wq, float* __restrict__ cs) {
  int gate = blockIdx.x;
  int j = threadIdx.x;
  const float* W = gate == 0 ? Wf : gate == 1 ? Wi : gate == 2 ? Wg : Wo;
  const float* row = W + (size_t)j * DW + DIN;
  float amax = 1e-8f;
#pragma unroll 4
  for (int k4 = 0; k4 < 64; ++k4) {
    f4 v = *(const f4*)(row + 4 * k4);
    amax = fmaxf(amax, fmaxf(fmaxf(fabsf(v[0]), fabsf(v[1])),
                             fmaxf(fabsf(v[2]), fabsf(v[3]))));
  }
  int gr = gate * 256 + j;
  cs[gr] = amax / (127.f * 127.f);
  float inv = 127.f / amax;
  signed char* dst = wq + (size_t)gr * 256;
#pragma unroll 4
  for (int k4 = 0; k4 < 64; ++k4) {
    f4 v = *(const f4*)(row + 4 * k4);
#pragma unroll
    for (int u = 0; u < 4; ++u)
      dst[4 * k4 + u] = (signed char)__float2int_rn(v[u] * inv);
  }
}

// ---------------------------------------------------------------------------
// Phase 1 (MFMA v3, r15-exact — 62us measured): Xg = x.Wx^T + bias.
// ---------------------------------------------------------------------------
__launch_bounds__(256, 2)
__global__ void kxgemm(const float* __restrict__ x,
                       const h8* __restrict__ wxfs,
                       const float* __restrict__ bf, const float* __restrict__ bi,
                       const float* __restrict__ bg, const float* __restrict__ bo,
                       _Float16* __restrict__ Xg,
                       int t0) {
  __shared__ char pool[65536];
  h8 (*xsf)[8][64] = (h8(*)[8][64])pool;               // 32KB A-frags
  h8 (*bs)[1024] = (h8(*)[1024])(pool + 32768);        // 2x16KB B slabs

  int tid = threadIdx.x;
  int l = tid & 63;
  int w = tid >> 6;
  int li = l & 15, lg = l >> 4;
  int tl = blockIdx.x >> 2;
  int nb = blockIdx.x & 3;
  int m0 = w * 16;

#pragma unroll
  for (int i = 0; i < 8; ++i) {
    int hi = tid + 256 * i;
    int sw  = hi >> 9;
    int sks = (hi >> 6) & 7;
    int sl  = hi & 63;
    int sli = sl & 15, slg = sl >> 4;
    const float* src = x + ((size_t)(t0 + tl) * NB + sw * 16 + sli) * DIN
                     + sks * 32 + slg * 8;
    f4 a0 = *(const f4*)src;
    f4 a1 = *(const f4*)(src + 4);
    h8 a;
    a[0] = (_Float16)a0[0]; a[1] = (_Float16)a0[1];
    a[2] = (_Float16)a0[2]; a[3] = (_Float16)a0[3];
    a[4] = (_Float16)a1[0]; a[5] = (_Float16)a1[1];
    a[6] = (_Float16)a1[2]; a[7] = (_Float16)a1[3];
    xsf[sw][sks][sl] = a;
  }
  {
    const h8* wsrc = wxfs + (size_t)(nb * 8 + 0) * 1024;
#pragma unroll
    for (int i = 0; i < 4; ++i) bs[0][tid + 256 * i] = wsrc[tid + 256 * i];
  }
  __syncthreads();

  f32x4 acc[16];
#pragma unroll
  for (int nt = 0; nt < 16; ++nt) {
    acc[nt][0] = 0.f; acc[nt][1] = 0.f; acc[nt][2] = 0.f; acc[nt][3] = 0.f;
  }

  for (int ks = 0; ks < 8; ++ks) {
    int buf = ks & 1;
    h8 ld0, ld1, ld2, ld3;
    if (ks < 7) {
      const h8* wn = wxfs + (size_t)(nb * 8 + ks + 1) * 1024;
      ld0 = wn[tid]; ld1 = wn[tid + 256]; ld2 = wn[tid + 512]; ld3 = wn[tid + 768];
    }
    h8 a = xsf[w][ks][l];
#pragma unroll
    for (int nt = 0; nt < 16; ++nt) {
      h8 bb = bs[buf][nt * 64 + l];
      acc[nt] = __builtin_amdgcn_mfma_f32_16x16x32_f16(a, bb, acc[nt], 0, 0, 0);
    }
    if (ks < 7) {
      h8* bt = bs[buf ^ 1];
      bt[tid] = ld0; bt[tid + 256] = ld1; bt[tid + 512] = ld2; bt[tid + 768] = ld3;
    }
    __syncthreads();
  }

  _Float16* osw = (_Float16*)(pool + (size_t)w * 8448);   // [16][264]
  const float* biasp = nb == 0 ? bf : nb == 1 ? bi : nb == 2 ? bg : bo;
#pragma unroll
  for (int nt = 0; nt < 16; ++nt) {
    float bv = biasp[nt * 16 + li];
#pragma unroll
    for (int r = 0; r < 4; ++r)
      osw[(lg * 4 + r) * 264 + nt * 16 + li] = (_Float16)(acc[nt][r] + bv);
  }
  _Float16* og = Xg + (size_t)tl * 65536 + (size_t)m0 * 1024 + nb * 256;
#pragma unroll
  for (int it = 0; it < 8; ++it) {
    int i = l + 64 * it;
    int row = i >> 5, c8 = i & 31;
    h8 v = *(const h8*)(const void*)&osw[row * 264 + c8 * 8];
    *(h8*)(void*)(og + (size_t)row * 1024 + c8 * 8) = v;
  }
}

// ---------------------------------------------------------------------------
// Phase 2: sequential LSTM, INT8 recurrent weights + int8 h, v_dot4_i32_i8.
// 512 threads; thread (j = tid>>1, p = tid&1) owns all 4 gate rows of unit j
// over its K-half as 4x8 named i4v (128 VGPRs) — whole weight set register-
// resident (~22-reg overflow handled implicitly, r7-style). LDS per step:
// 8 x b128 h-broadcast reads only (halves skewed 16B -> disjoint banks);
// weight-tail LDS reads GONE. preact_h = cs[row] * sdot4-accum; x-part (f16
// MFMA) added once via p-conditional seed + DPP pair-combine.
// 86KB referenced LDS pool pins the occupancy heuristic (r12) so grant=128.
// ---------------------------------------------------------------------------
#define CH8(M) M(0) M(1) M(2) M(3) M(4) M(5) M(6) M(7)
#define HB 144   // byte stride of one K-half in h buffer (128 + 16 skew)

__global__ __launch_bounds__(512, 1)
void klstm(const signed char* __restrict__ wq, const float* __restrict__ cs,
           const _Float16* __restrict__ Xg,
           const float* __restrict__ hsrc, const float* __restrict__ csrc,
           float* __restrict__ out,
           float* __restrict__ hN, float* __restrict__ cN,
           int t0, int Tc) {
  __shared__ __align__(16) char hpool[2][43008];   // 84KB pool; h at head

  int tid = threadIdx.x;
  int b = blockIdx.x;
  int p = tid & 1;
  int j = tid >> 1;

  const i4v* rF = (const i4v*)(wq + ((size_t)(0 * DH + j) * 256) + p * 128);
  const i4v* rI = (const i4v*)(wq + ((size_t)(1 * DH + j) * 256) + p * 128);
  const i4v* rG = (const i4v*)(wq + ((size_t)(2 * DH + j) * 256) + p * 128);
  const i4v* rO = (const i4v*)(wq + ((size_t)(3 * DH + j) * 256) + p * 128);

  // --- weights: 8 i4v chunks per gate row, named + pinned (r7 pattern) ---
#define DECLW(c) i4v QF_##c, QI_##c, QG_##c, QO_##c;
  CH8(DECLW)
#undef DECLW
#define LOADW(c) \
  QF_##c = rF[c]; QI_##c = rI[c]; QG_##c = rG[c]; QO_##c = rO[c];
  CH8(LOADW)
#undef LOADW
#define PINW(c) \
  asm volatile("" : "+v"(QF_##c)); asm volatile("" : "+v"(QI_##c)); \
  asm volatile("" : "+v"(QG_##c)); asm volatile("" : "+v"(QO_##c));
  CH8(PINW)
#undef PINW

  float cF = cs[0 * DH + j];
  float cI = cs[1 * DH + j];
  float cG = cs[2 * DH + j];
  float cO = cs[3 * DH + j];

  float creg = csrc[(size_t)b * DH + j];
  if (tid < 256) {
    // quantize h0 element tid -> skewed byte position
    int pos = (tid < 128) ? tid : (HB + tid - 128);
    float hv = hsrc[(size_t)b * DH + tid];
    hpool[0][pos] = (char)__float2int_rn(fminf(fmaxf(hv, -1.f), 1.f) * 127.f);
  }
  __syncthreads();

  const size_t xstep = (size_t)NB * G4;
  const _Float16* xpA = Xg + (size_t)b * G4 + p * 512 + j;   // f or g
  const _Float16* xpB = xpA + 256;                           // i or o
  float xA = (float)xpA[0], xB = (float)xpB[0];
  float hlast = 0.f;

  for (int t = 0; t < Tc; ++t) {
    float xAn = 0.f, xBn = 0.f;
    if (t + 1 < Tc) {
      xAn = (float)xpA[(size_t)(t + 1) * xstep];
      xBn = (float)xpB[(size_t)(t + 1) * xstep];
    }
    const char* hb = hpool[t & 1] + p * HB;

    int aF = 0, aI = 0, aG = 0, aO = 0;
#define DOTC(c) { \
    i4v hv = *(const i4v*)(const void*)(hb + 16 * (c)); \
    aF = sdot4_(QF_##c[0], hv[0], aF); aF = sdot4_(QF_##c[1], hv[1], aF); \
    aF = sdot4_(QF_##c[2], hv[2], aF); aF = sdot4_(QF_##c[3], hv[3], aF); \
    aI = sdot4_(QI_##c[0], hv[0], aI); aI = sdot4_(QI_##c[1], hv[1], aI); \
    aI = sdot4_(QI_##c[2], hv[2], aI); aI = sdot4_(QI_##c[3], hv[3], aI); \
    aG = sdot4_(QG_##c[0], hv[0], aG); aG = sdot4_(QG_##c[1], hv[1], aG); \
    aG = sdot4_(QG_##c[2], hv[2], aG); aG = sdot4_(QG_##c[3], hv[3], aG); \
    aO = sdot4_(QO_##c[0], hv[0], aO); aO = sdot4_(QO_##c[1], hv[1], aO); \
    aO = sdot4_(QO_##c[2], hv[2], aO); aO = sdot4_(QO_##c[3], hv[3], aO); }
    CH8(DOTC)
#undef DOTC

    // scale to float + seed x once (p-conditional) + pair-combine via DPP
    float vF = cF * (float)aF + (p ? 0.f : xA);
    float vI = cI * (float)aI + (p ? 0.f : xB);
    float vG = cG * (float)aG + (p ? xA : 0.f);
    float vO = cO * (float)aO + (p ? xB : 0.f);
    vF += dpp_swap1(vF);
    vI += dpp_swap1(vI);
    vG += dpp_swap1(vG);
    vO += dpp_swap1(vO);

    float f_ = sigmoid_(vF);
    float i_ = sigmoid_(vI);
    float g_ = tanh_(vG);
    float o_ = sigmoid_(vO);

    creg = f_ * creg + i_ * g_;
    float hn = o_ * tanh_(creg);
    hlast = hn;
    if (p == 0) {
      out[((size_t)(t0 + t) * NB + b) * DH + j] = hn;
    } else {
      int pos = (j < 128) ? j : (HB + j - 128);
      hpool[(t + 1) & 1][pos] = (char)__float2int_rn(hn * 127.f);
    }
    __syncthreads();
    xA = xAn; xB = xBn;
  }

  if (p == 0) {
    hN[(size_t)b * DH + j] = hlast;
    cN[(size_t)b * DH + j] = creg;
  }
}

// ---------------------------------------------------------------------------
extern "C" void kernel_launch(void* const* d_in, const int* in_sizes, int n_in,
                              void* d_out, int out_size, void* d_ws, size_t ws_size,
                              hipStream_t stream) {
  if (n_in < 11) return;
  const float* x  = (const float*)d_in[0];
  const float* h0 = (const float*)d_in[1];
  const float* c0 = (const float*)d_in[2];
  const float* Wf = (const float*)d_in[3];
  const float* bf = (const float*)d_in[4];
  const float* Wi = (const float*)d_in[5];
  const float* bi = (const float*)d_in[6];
  const float* Wg = (const float*)d_in[7];
  const float* bg = (const float*)d_in[8];
  const float* Wo = (const float*)d_in[9];
  const float* bo = (const float*)d_in[10];

  float* out = (float*)d_out;
  float* hN = out + (size_t)T_STEPS * NB * DH;
  float* cN = hN + (size_t)NB * DH;

  // ws layout: [Xg ring: Tc*128KB][wxfs 512KB][wq 256KB][cs 4KB]
  const size_t wxfBytes = (size_t)G4 * 128 * sizeof(h2);   // 512KB
  const size_t wqBytes  = (size_t)G4 * 256;                // 256KB
  const size_t csBytes  = (size_t)G4 * sizeof(float);      // 4KB
  const size_t fixedBytes = wxfBytes + wqBytes + csBytes;
  size_t avail = (ws_size > fixedBytes + 512) ? ws_size - fixedBytes - 512 : 0;
  const size_t perT = (size_t)NB * G4 * 2;  // 128KB per time step
  int Tc = (int)(avail / perT);
  if (Tc > T_STEPS) Tc = T_STEPS;
  if (Tc < 1) Tc = 1;

  _Float16* Xg = (_Float16*)d_ws;
  size_t xgBytes = ((size_t)Tc * perT + 255) / 256 * 256;
  h2* wxfs = (h2*)((char*)d_ws + xgBytes);
  signed char* wq = (signed char*)((char*)d_ws + xgBytes + wxfBytes);
  float* cs = (float*)((char*)d_ws + xgBytes + wxfBytes + wqBytes);

  kconv_w<<<dim3(512), dim3(256), 0, stream>>>(Wf, Wi, Wg, Wo, wxfs);
  kscale<<<dim3(4), dim3(256), 0, stream>>>(Wf, Wi, Wg, Wo, wq, cs);

  for (int t0 = 0; t0 < T_STEPS; t0 += Tc) {
    int tc = (T_STEPS - t0 < Tc) ? (T_STEPS - t0) : Tc;
    kxgemm<<<dim3(tc * 4), dim3(256), 0, stream>>>(x, (const h8*)wxfs,
                                                   bf, bi, bg, bo, Xg, t0);
    const float* hs = (t0 == 0) ? h0 : hN;
    const float* cs_ = (t0 == 0) ? c0 : cN;
    klstm<<<dim3(NB), dim3(512), 0, stream>>>(wq, cs, Xg, hs, cs_,
                                              out, hN, cN, t0, tc);
  }
}